// Round 8
// baseline (504.110 us; speedup 1.0000x reference)
//
#include <hip/hip_runtime.h>
#include <cstdint>
#include <cstddef>

// Problem constants (B=2, S=2048, D=1024, H=16, DH=64, DM=4096)
#define SEQ    2048
#define DMODEL 1024
#define NHEAD  16
#define DHEAD  64
#define DMLP   4096
#define ROWS   4096   // B*S

typedef __attribute__((ext_vector_type(8))) short bf16x8v;  // 8 bf16 (4 VGPRs)
typedef __attribute__((ext_vector_type(4))) float f32x4;

// scale folded into Q projection: 1/sqrt(DH) * log2(e), so softmax uses exp2
#define QSCALE 0.18033688011112042f

// ---------------------------------------------------------------- utilities
__device__ __forceinline__ float wave_reduce_sum(float v) {
#pragma unroll
  for (int off = 32; off; off >>= 1) v += __shfl_xor(v, off, 64);
  return v;
}
__device__ __forceinline__ float gelu_new(float x) {
  // 0.5*x*(1+tanh(sqrt(2/pi)*(x+0.044715*x^3)))  (jax.nn.gelu approximate=True)
  const float c = 0.7978845608028654f;
  float inner = c * (x + 0.044715f * x * x * x);
  return 0.5f * x * (1.0f + tanhf(inner));
}
__device__ __forceinline__ unsigned short f2bf(float x) {  // RNE f32->bf16
  union { float f; unsigned u; } v; v.f = x;
  unsigned r = v.u + 0x7fffu + ((v.u >> 16) & 1u);
  return (unsigned short)(r >> 16);
}
// async global->LDS, 16B per lane (global addr per-lane; LDS base wave-uniform)
__device__ __forceinline__ void gload_lds16(const void* g, void* l) {
  __builtin_amdgcn_global_load_lds(
      (const __attribute__((address_space(1))) unsigned int*)g,
      (__attribute__((address_space(3))) unsigned int*)l, 16, 0, 0);
}

// ---------------------------------------------------------------- LayerNorm
// TransformerLens LN -> bf16 output (feeds MFMA GEMMs).
__global__ __launch_bounds__(256)
void ln_bf16_kernel(const float* __restrict__ x, const float* __restrict__ w,
                    const float* __restrict__ b, unsigned short* __restrict__ y) {
  __shared__ float sred[4];
  const int r = blockIdx.x;
  const int t = threadIdx.x;
  const int wid = t >> 6, lane = t & 63;
  const float4 v = ((const float4*)(x + (size_t)r * DMODEL))[t];

  float s = v.x + v.y + v.z + v.w;
  s = wave_reduce_sum(s);
  if (lane == 0) sred[wid] = s;
  __syncthreads();
  const float mean = (sred[0] + sred[1] + sred[2] + sred[3]) * (1.0f / DMODEL);
  __syncthreads();

  float4 c;
  c.x = v.x - mean; c.y = v.y - mean; c.z = v.z - mean; c.w = v.w - mean;
  float ss = c.x * c.x + c.y * c.y + c.z * c.z + c.w * c.w;
  ss = wave_reduce_sum(ss);
  if (lane == 0) sred[wid] = ss;
  __syncthreads();
  const float rs =
      rsqrtf((sred[0] + sred[1] + sred[2] + sred[3]) * (1.0f / DMODEL) + 1e-5f);

  const float4 wv = ((const float4*)w)[t];
  const float4 bv = ((const float4*)b)[t];
  ushort4 o;
  o.x = f2bf(c.x * rs * wv.x + bv.x);
  o.y = f2bf(c.y * rs * wv.y + bv.y);
  o.z = f2bf(c.z * rs * wv.z + bv.z);
  o.w = f2bf(c.w * rs * wv.w + bv.w);
  ((ushort4*)(y + (size_t)r * DMODEL))[t] = o;
}

// ------------------------------------------------- weight convert/transpose
// Generic 64x64-tile transpose + f32->bf16: dst[c][r] = src[r][c].
__global__ __launch_bounds__(256)
void transpose_cvt(const float* __restrict__ src, unsigned short* __restrict__ dst,
                   int ld_src, int ld_dst) {
  __shared__ float t[64][68];
  const int r0 = blockIdx.y * 64, c0 = blockIdx.x * 64;
  const int tid = threadIdx.x;
  const int c4 = (tid & 15) * 4, r = tid >> 4;
#pragma unroll
  for (int p = 0; p < 4; ++p) {
    const float4 v = *(const float4*)(src + (size_t)(r0 + r + p * 16) * ld_src + c0 + c4);
    *(float4*)&t[r + p * 16][c4] = v;
  }
  __syncthreads();
  const int r4 = (tid & 15) * 4, c = tid >> 4;
#pragma unroll
  for (int p = 0; p < 4; ++p) {
    const int cc = c + p * 16;
    ushort4 o;
    o.x = f2bf(t[r4 + 0][cc]);
    o.y = f2bf(t[r4 + 1][cc]);
    o.z = f2bf(t[r4 + 2][cc]);
    o.w = f2bf(t[r4 + 3][cc]);
    *(ushort4*)(dst + (size_t)(c0 + cc) * ld_dst + r0 + r4) = o;
  }
}

// W_{Q,K,V}[H, D, DH] f32 -> Bt[h*64+dh][d] bf16 (3 weights, contiguous out).
__global__ __launch_bounds__(256)
void cvt_wqkv(const float* __restrict__ Wq, const float* __restrict__ Wk,
              const float* __restrict__ Wv, unsigned short* __restrict__ out) {
  __shared__ float t[64][68];
  const float* src = (blockIdx.z == 0) ? Wq : (blockIdx.z == 1) ? Wk : Wv;
  unsigned short* dst = out + (size_t)blockIdx.z * (DMODEL * NHEAD * DHEAD);
  const int h = blockIdx.y, d0 = blockIdx.x * 64;
  const int tid = threadIdx.x;
  const int c4 = (tid & 15) * 4, r = tid >> 4;
#pragma unroll
  for (int p = 0; p < 4; ++p) {
    const float4 v = *(const float4*)(src + (size_t)h * (DMODEL * DHEAD) +
                                      (size_t)(d0 + r + p * 16) * DHEAD + c4);
    *(float4*)&t[r + p * 16][c4] = v;
  }
  __syncthreads();
  const int r4 = (tid & 15) * 4, c = tid >> 4;
#pragma unroll
  for (int p = 0; p < 4; ++p) {
    const int cc = c + p * 16;  // dh index
    ushort4 o;
    o.x = f2bf(t[r4 + 0][cc]);
    o.y = f2bf(t[r4 + 1][cc]);
    o.z = f2bf(t[r4 + 2][cc]);
    o.w = f2bf(t[r4 + 3][cc]);
    *(ushort4*)(dst + (size_t)(h * 64 + cc) * DMODEL + d0 + r4) = o;
  }
}

// ---------------------------------------------------------------- MFMA GEMM
// C[M x N] = A[M x K](bf16,row-major) @ Bt[N x K](bf16,row-major)^T + bias.
// m97 structure: 128x128 tile, BK=32, 4 waves, global_load_lds w16, 2 barriers.
// EPI: 0 = f32 store; 1 = bf16 gelu store; 2 = f32 + addend; 3 = f32 accum;
//      4 = bf16 TRANSPOSED store (Cout[col][ldc] layout, packed ushort4);
//      5 = bf16 store.
template <int EPI>
__global__ __launch_bounds__(256)
void gemm_bf16(const unsigned short* __restrict__ A,
               const unsigned short* __restrict__ Bt,
               const float* __restrict__ bias, const float* __restrict__ addend,
               void* __restrict__ Cout, int ldc, int K) {
  __shared__ unsigned short As[128 * 32];  // [row][k] linear, rows of 64B
  __shared__ unsigned short Bs[128 * 32];
  const int tid = threadIdx.x;
  const int w = tid >> 6, lane = tid & 63;
  const int wr = w >> 1, wc = w & 1;           // wave -> 64x64 quadrant
  const int m0 = blockIdx.x * 128, n0 = blockIdx.y * 128;

  f32x4 acc[4][4];
#pragma unroll
  for (int m = 0; m < 4; ++m)
#pragma unroll
    for (int n = 0; n < 4; ++n) acc[m][n] = (f32x4){0.f, 0.f, 0.f, 0.f};

  const int srow = w * 32 + (lane >> 2);       // staging row within tile
  const int scol = (lane & 3) * 8;             // staging k-offset (8 bf16 = 16B)

  for (int k0 = 0; k0 < K; k0 += 32) {
    __syncthreads();  // all waves done reading previous tile
#pragma unroll
    for (int it = 0; it < 2; ++it) {
      const int row = srow + it * 16;
      gload_lds16(A + (size_t)(m0 + row) * K + k0 + scol,
                  &As[(w * 32 + it * 16) * 32]);
      gload_lds16(Bt + (size_t)(n0 + row) * K + k0 + scol,
                  &Bs[(w * 32 + it * 16) * 32]);
    }
    __syncthreads();  // staging complete (vmcnt drained at barrier)

    bf16x8v af[4], bf[4];
#pragma unroll
    for (int m = 0; m < 4; ++m)
      af[m] = *(const bf16x8v*)&As[(wr * 64 + m * 16 + (lane & 15)) * 32 + (lane >> 4) * 8];
#pragma unroll
    for (int n = 0; n < 4; ++n)
      bf[n] = *(const bf16x8v*)&Bs[(wc * 64 + n * 16 + (lane & 15)) * 32 + (lane >> 4) * 8];
#pragma unroll
    for (int m = 0; m < 4; ++m)
#pragma unroll
      for (int n = 0; n < 4; ++n)
        acc[m][n] = __builtin_amdgcn_mfma_f32_16x16x32_bf16(af[m], bf[n], acc[m][n], 0, 0, 0);
  }

  // epilogue: C/D layout col = lane&15, row = (lane>>4)*4 + reg  [m89]
#pragma unroll
  for (int m = 0; m < 4; ++m) {
    const int row = m0 + wr * 64 + m * 16 + (lane >> 4) * 4;
#pragma unroll
    for (int n = 0; n < 4; ++n) {
      const int col = n0 + wc * 64 + n * 16 + (lane & 15);
      const float bcol = bias[col];
      const f32x4 a = acc[m][n];
      if (EPI == 4) {
        // transposed bf16 store: 4 contiguous rows in dst row `col`
        ushort4 o;
        o.x = f2bf(a[0] + bcol); o.y = f2bf(a[1] + bcol);
        o.z = f2bf(a[2] + bcol); o.w = f2bf(a[3] + bcol);
        *(ushort4*)((unsigned short*)Cout + (size_t)col * ldc + row) = o;
      } else {
#pragma unroll
        for (int r = 0; r < 4; ++r) {
          const float val = a[r] + bcol;
          const size_t off = (size_t)(row + r) * ldc + col;
          if (EPI == 0) {
            ((float*)Cout)[off] = val;
          } else if (EPI == 1) {
            ((unsigned short*)Cout)[off] = f2bf(gelu_new(val));
          } else if (EPI == 2) {
            ((float*)Cout)[off] = val + addend[off];
          } else if (EPI == 3) {
            ((float*)Cout)[off] += val;
          } else {  // EPI == 5
            ((unsigned short*)Cout)[off] = f2bf(val);
          }
        }
      }
    }
  }
}

// ------------------------------------------- fused QKV GEMM (N = 3072)
// C[4096 x 3072] = xln @ (WQt||WKt||WVt)^T; per-block epilogue switch:
// blockIdx.y>>3 = 0 -> Qb (bf16, PRE-SCALED by QSCALE for exp2 softmax),
// 1 -> Kb (bf16), 2 -> Vt (bf16 transposed).
__global__ __launch_bounds__(256)
void gemm_qkv(const unsigned short* __restrict__ A,
              const unsigned short* __restrict__ Bt,  // [3072][1024]
              const float* __restrict__ bQ, const float* __restrict__ bK,
              const float* __restrict__ bV,
              unsigned short* __restrict__ Qb, unsigned short* __restrict__ Kb,
              unsigned short* __restrict__ Vt) {
  __shared__ unsigned short As[128 * 32];
  __shared__ unsigned short Bs[128 * 32];
  const int tid = threadIdx.x;
  const int w = tid >> 6, lane = tid & 63;
  const int wr = w >> 1, wc = w & 1;
  const int m0 = blockIdx.x * 128, n0 = blockIdx.y * 128;

  f32x4 acc[4][4];
#pragma unroll
  for (int m = 0; m < 4; ++m)
#pragma unroll
    for (int n = 0; n < 4; ++n) acc[m][n] = (f32x4){0.f, 0.f, 0.f, 0.f};

  const int srow = w * 32 + (lane >> 2);
  const int scol = (lane & 3) * 8;

  for (int k0 = 0; k0 < DMODEL; k0 += 32) {
    __syncthreads();
#pragma unroll
    for (int it = 0; it < 2; ++it) {
      const int row = srow + it * 16;
      gload_lds16(A + (size_t)(m0 + row) * DMODEL + k0 + scol,
                  &As[(w * 32 + it * 16) * 32]);
      gload_lds16(Bt + (size_t)(n0 + row) * DMODEL + k0 + scol,
                  &Bs[(w * 32 + it * 16) * 32]);
    }
    __syncthreads();

    bf16x8v af[4], bf[4];
#pragma unroll
    for (int m = 0; m < 4; ++m)
      af[m] = *(const bf16x8v*)&As[(wr * 64 + m * 16 + (lane & 15)) * 32 + (lane >> 4) * 8];
#pragma unroll
    for (int n = 0; n < 4; ++n)
      bf[n] = *(const bf16x8v*)&Bs[(wc * 64 + n * 16 + (lane & 15)) * 32 + (lane >> 4) * 8];
#pragma unroll
    for (int m = 0; m < 4; ++m)
#pragma unroll
      for (int n = 0; n < 4; ++n)
        acc[m][n] = __builtin_amdgcn_mfma_f32_16x16x32_bf16(af[m], bf[n], acc[m][n], 0, 0, 0);
  }

  const int which = blockIdx.y >> 3;  // uniform per block: 0=Q, 1=K, 2=V
  const float* bias = (which == 0) ? bQ : (which == 1) ? bK : bV;
#pragma unroll
  for (int m = 0; m < 4; ++m) {
    const int row = m0 + wr * 64 + m * 16 + (lane >> 4) * 4;
#pragma unroll
    for (int n = 0; n < 4; ++n) {
      const int col = (n0 + wc * 64 + n * 16 + (lane & 15)) & 1023;  // within matrix
      const float bcol = bias[col];
      const f32x4 a = acc[m][n];
      if (which == 2) {  // V: transposed store Vt[col][row]
        ushort4 o;
        o.x = f2bf(a[0] + bcol); o.y = f2bf(a[1] + bcol);
        o.z = f2bf(a[2] + bcol); o.w = f2bf(a[3] + bcol);
        *(ushort4*)(Vt + (size_t)col * ROWS + row) = o;
      } else if (which == 1) {
#pragma unroll
        for (int r = 0; r < 4; ++r)
          Kb[(size_t)(row + r) * DMODEL + col] = f2bf(a[r] + bcol);
      } else {  // Q: pre-scale for exp2 softmax
#pragma unroll
        for (int r = 0; r < 4; ++r)
          Qb[(size_t)(row + r) * DMODEL + col] = f2bf((a[r] + bcol) * QSCALE);
      }
    }
  }
}

// ---------------------------------------------------------------- Attention
// Causal MFMA flash attention, bf16 inputs, fp32 accum, swapped-operand form
// (S^T: col=q, row=key -> lane-local softmax stats, 2 shfl_xor per reduce).
// Q pre-scaled by 1/sqrt(DH)*log2(e) -> softmax via raw v_exp_f32 (exp2).
// Occupancy: 512 blocks x 8 waves (4 waves/SIMD co-resident). Wave w<4 owns
// a 16-query tile of qblk=pr; w>=4 of qblk=31-pr. Waves w and w+4 share a
// SIMD (round-robin) -> per-SIMD chunk total = (pr+1)+(32-pr) = 33, uniform.
// XCD locality: bid = pr*32 + bh so bid%8 == bh%8 -> one (b,h)'s 512 KB
// K+V slab serves 16 blocks on one XCD's L2.
// Pipeline: next chunk's K fragments prefetched during current chunk;
// V loads issued before softmax; mask only on the diagonal chunk.
__global__ __launch_bounds__(512)
void attn_mfma_kernel(const unsigned short* __restrict__ Qb,
                      const unsigned short* __restrict__ Kb,
                      const unsigned short* __restrict__ Vt,
                      unsigned short* __restrict__ Zb) {
  __shared__ unsigned short Ps[8][16][72];  // per-wave P: [qloc][key], padded
  const int tid = threadIdx.x;
  const int w = tid >> 6, lane = tid & 63;
  const int lg = lane >> 4, lr = lane & 15;
  const int bh = blockIdx.x & 31;          // b*16 + h  (bid%8 == bh%8)
  const int pr = blockIdx.x >> 5;          // pair index 0..15
  const int h = bh & 15, b = bh >> 4;
  const size_t qk_base = (size_t)b * SEQ * DMODEL + (size_t)h * DHEAD;
  const size_t vt_base = (size_t)(h * DHEAD) * ROWS + (size_t)b * SEQ;

  const int qblk = (w < 4) ? pr : (31 - pr);
  const int q0 = qblk * 64 + (w & 3) * 16; // wave's first query
  const int myq = q0 + lr;                 // this lane's query (col index)
  const int jlast = qblk * 64;             // last (diagonal) chunk start

  // Q B-fragment: col=lr -> query myq, k(dim) = ks*32 + lg*8 + 0..7
  bf16x8v bq[2];
#pragma unroll
  for (int ks = 0; ks < 2; ++ks)
    bq[ks] = *(const bf16x8v*)&Qb[qk_base + (size_t)myq * DMODEL + ks * 32 + lg * 8];

  f32x4 accz[4];
#pragma unroll
  for (int nd = 0; nd < 4; ++nd) accz[nd] = (f32x4){0.f, 0.f, 0.f, 0.f};
  float mq = -3.0e38f, Lq = 0.0f;

  // prefetch K fragments for first chunk
  bf16x8v kf[2][4];
#pragma unroll
  for (int ks = 0; ks < 2; ++ks)
#pragma unroll
    for (int n = 0; n < 4; ++n)
      kf[ks][n] = *(const bf16x8v*)
          &Kb[qk_base + (size_t)(n * 16 + lr) * DMODEL + ks * 32 + lg * 8];

  for (int jc = 0; jc <= jlast; jc += 64) {
    // ---- QK^T swapped: accs[n] = K_tile_n . Q^T ; row=key(4lg+r), col=q(lr)
    f32x4 accs[4];
#pragma unroll
    for (int n = 0; n < 4; ++n) accs[n] = (f32x4){0.f, 0.f, 0.f, 0.f};
#pragma unroll
    for (int ks = 0; ks < 2; ++ks)
#pragma unroll
      for (int n = 0; n < 4; ++n)
        accs[n] = __builtin_amdgcn_mfma_f32_16x16x32_bf16(kf[ks][n], bq[ks], accs[n], 0, 0, 0);

    // ---- prefetch next chunk's K fragments (hidden under softmax+PV)
    const int jn = jc + 64;
    if (jn <= jlast) {
#pragma unroll
      for (int ks = 0; ks < 2; ++ks)
#pragma unroll
        for (int n = 0; n < 4; ++n)
          kf[ks][n] = *(const bf16x8v*)
              &Kb[qk_base + (size_t)(jn + n * 16 + lr) * DMODEL + ks * 32 + lg * 8];
    }
    // ---- V fragments issued early (independent of softmax)
    bf16x8v vf[2][4];
#pragma unroll
    for (int ks = 0; ks < 2; ++ks)
#pragma unroll
      for (int nd = 0; nd < 4; ++nd)
        vf[ks][nd] = *(const bf16x8v*)
            &Vt[vt_base + (size_t)(nd * 16 + lr) * ROWS + jc + ks * 32 + lg * 8];

    // ---- mask only on diagonal chunk; lane-local max (scores pre-scaled)
    float mx = -3.0e38f;
    if (jc == jlast) {
#pragma unroll
      for (int n = 0; n < 4; ++n)
#pragma unroll
        for (int r = 0; r < 4; ++r) {
          float s = accs[n][r];
          s = (jc + n * 16 + 4 * lg + r <= myq) ? s : -3.0e38f;  // causal
          accs[n][r] = s; mx = fmaxf(mx, s);
        }
    } else {
#pragma unroll
      for (int n = 0; n < 4; ++n)
#pragma unroll
        for (int r = 0; r < 4; ++r) mx = fmaxf(mx, accs[n][r]);
    }
    mx = fmaxf(mx, __shfl_xor(mx, 16, 64));
    mx = fmaxf(mx, __shfl_xor(mx, 32, 64));
    const float mn = fmaxf(mq, mx);
    const float c0 = __builtin_amdgcn_exp2f(mq - mn);
    // ---- exp2, packed P^T writes to LDS [q][key], lane-local partial sum
    float sum = 0.0f;
#pragma unroll
    for (int n = 0; n < 4; ++n) {
      ushort4 pk;
      float e0 = __builtin_amdgcn_exp2f(accs[n][0] - mn);
      float e1 = __builtin_amdgcn_exp2f(accs[n][1] - mn);
      float e2 = __builtin_amdgcn_exp2f(accs[n][2] - mn);
      float e3 = __builtin_amdgcn_exp2f(accs[n][3] - mn);
      sum += e0 + e1 + e2 + e3;
      pk.x = f2bf(e0); pk.y = f2bf(e1); pk.z = f2bf(e2); pk.w = f2bf(e3);
      *(ushort4*)&Ps[w][lr][n * 16 + 4 * lg] = pk;
    }
    sum += __shfl_xor(sum, 16, 64);
    sum += __shfl_xor(sum, 32, 64);
    Lq = Lq * c0 + sum;
    mq = mn;
#pragma unroll
    for (int nd = 0; nd < 4; ++nd) accz[nd] *= c0;
    // ---- P A-side read (same-wave DS ordering): row=q(lr), k=keys
    bf16x8v ap[2];
#pragma unroll
    for (int ks = 0; ks < 2; ++ks)
      ap[ks] = *(const bf16x8v*)&Ps[w][lr][ks * 32 + lg * 8];
    // ---- PV swapped: accz[nd] = V^T_tile . P ; row=d(4lg+r), col=q(lr)
#pragma unroll
    for (int ks = 0; ks < 2; ++ks)
#pragma unroll
      for (int nd = 0; nd < 4; ++nd)
        accz[nd] = __builtin_amdgcn_mfma_f32_16x16x32_bf16(vf[ks][nd], ap[ks], accz[nd], 0, 0, 0);
  }
  // ---- epilogue: lane's query row, d = nd*16 + 4lg + (0..3) contiguous
  const float rL = 1.0f / Lq;
  unsigned short* zrow = Zb + (size_t)((size_t)b * SEQ + myq) * DMODEL + h * DHEAD;
#pragma unroll
  for (int nd = 0; nd < 4; ++nd) {
    ushort4 o;
    o.x = f2bf(accz[nd][0] * rL);
    o.y = f2bf(accz[nd][1] * rL);
    o.z = f2bf(accz[nd][2] * rL);
    o.w = f2bf(accz[nd][3] * rL);
    *(ushort4*)(zrow + nd * 16 + 4 * lg) = o;
  }
}

// ---------------------------------------------------------------- launch
extern "C" void kernel_launch(void* const* d_in, const int* in_sizes, int n_in,
                              void* d_out, int out_size, void* d_ws, size_t ws_size,
                              hipStream_t stream) {
  const float* resid_pre = (const float*)d_in[0];
  const float* ln1_w = (const float*)d_in[1];
  const float* ln1_b = (const float*)d_in[2];
  const float* W_Q = (const float*)d_in[3];
  const float* W_K = (const float*)d_in[4];
  const float* W_V = (const float*)d_in[5];
  const float* W_O = (const float*)d_in[6];
  const float* b_Q = (const float*)d_in[7];
  const float* b_K = (const float*)d_in[8];
  const float* b_V = (const float*)d_in[9];
  const float* b_O = (const float*)d_in[10];
  const float* ln2_w = (const float*)d_in[11];
  const float* ln2_b = (const float*)d_in[12];
  const float* W_in = (const float*)d_in[13];
  const float* b_in = (const float*)d_in[14];
  const float* W_out = (const float*)d_in[15];
  const float* b_out = (const float*)d_in[16];
  (void)in_sizes; (void)n_in; (void)out_size; (void)ws_size;

  float* out = (float*)d_out;
  char* w8 = (char*)d_ws;
  // Workspace map (56 MB used):
  //  [0,8M)    xln_b (LN1 out / LN2 out) ; Zb aliases (dead-time disjoint)
  //  [8,14M)   WQt/WKt/WVt  bf16 [3072,1024] contiguous (B^T layout)
  //  [14,16M)  WOt   bf16 [1024,1024]
  //  [16,24M)  Wint  bf16 [4096,1024]
  //  [24,32M)  Woutt bf16 [1024,4096]
  //  [32,40M)  Qb bf16 [4096,1024]   \
  //  [40,48M)  Kb bf16 [4096,1024]    } dead after attn; hid_b [32,64M) reuses
  //  [48,56M)  Vt bf16 [1024,4096]   /
  unsigned short* xln_b = (unsigned short*)(w8);
  unsigned short* Zb    = (unsigned short*)(w8);
  unsigned short* WQt   = (unsigned short*)(w8 + (8u << 20));
  unsigned short* WOt   = (unsigned short*)(w8 + (14u << 20));
  unsigned short* Wint  = (unsigned short*)(w8 + (16u << 20));
  unsigned short* Woutt = (unsigned short*)(w8 + (24u << 20));
  unsigned short* Qb    = (unsigned short*)(w8 + (32u << 20));
  unsigned short* Kb    = (unsigned short*)(w8 + (40u << 20));
  unsigned short* Vt    = (unsigned short*)(w8 + (48u << 20));
  unsigned short* hid_b = (unsigned short*)(w8 + (32u << 20));

  // weight conversions (run every call; d_ws is re-poisoned)
  cvt_wqkv<<<dim3(16, 16, 3), 256, 0, stream>>>(W_Q, W_K, W_V, WQt);
  transpose_cvt<<<dim3(16, 16), 256, 0, stream>>>(W_O, WOt, DMODEL, DMODEL);
  transpose_cvt<<<dim3(64, 16), 256, 0, stream>>>(W_in, Wint, DMLP, DMODEL);
  transpose_cvt<<<dim3(16, 64), 256, 0, stream>>>(W_out, Woutt, DMODEL, DMLP);

  // LN1 -> bf16
  ln_bf16_kernel<<<ROWS, 256, 0, stream>>>(resid_pre, ln1_w, ln1_b, xln_b);
  // fused QKV projection -> Qb (pre-scaled), Kb, Vt(transposed)
  gemm_qkv<<<dim3(32, 24), 256, 0, stream>>>(xln_b, WQt, b_Q, b_K, b_V, Qb, Kb, Vt);
  // causal MFMA attention -> Zb (aliases xln_b; LN1 output is dead now)
  attn_mfma_kernel<<<512, 512, 0, stream>>>(Qb, Kb, Vt, Zb);
  // W_O projection + bias + residual -> d_out = resid_mid
  dim3 g1024(ROWS / 128, 1024 / 128);
  gemm_bf16<2><<<g1024, 256, 0, stream>>>(Zb, WOt, b_O, resid_pre, out, DMODEL, DMODEL);
  // LN2 -> bf16 (overwrites Zb region after W_O consumed it)
  ln_bf16_kernel<<<ROWS, 256, 0, stream>>>(out, ln2_w, ln2_b, xln_b);
  // MLP in + GELU -> bf16 hid
  dim3 gin(ROWS / 128, DMLP / 128);
  gemm_bf16<1><<<gin, 256, 0, stream>>>(xln_b, Wint, b_in, nullptr, hid_b, DMLP, DMODEL);
  // MLP out, accumulate into resid_mid in d_out
  gemm_bf16<3><<<g1024, 256, 0, stream>>>(hid_b, Woutt, b_out, nullptr, out, DMODEL, DMLP);
}

// Round 9
// 445.567 us; speedup vs baseline: 1.1314x; 1.1314x over previous
//
#include <hip/hip_runtime.h>
#include <cstdint>
#include <cstddef>

// Problem constants (B=2, S=2048, D=1024, H=16, DH=64, DM=4096)
#define SEQ    2048
#define DMODEL 1024
#define NHEAD  16
#define DHEAD  64
#define DMLP   4096
#define ROWS   4096   // B*S

typedef __attribute__((ext_vector_type(8))) short bf16x8v;  // 8 bf16 (4 VGPRs)
typedef __attribute__((ext_vector_type(4))) float f32x4;

// scale folded into Q projection: 1/sqrt(DH) * log2(e), so softmax uses exp2
#define QSCALE 0.18033688011112042f

// ---------------------------------------------------------------- utilities
__device__ __forceinline__ float wave_reduce_sum(float v) {
#pragma unroll
  for (int off = 32; off; off >>= 1) v += __shfl_xor(v, off, 64);
  return v;
}
__device__ __forceinline__ float gelu_new(float x) {
  // 0.5*x*(1+tanh(sqrt(2/pi)*(x+0.044715*x^3)))  (jax.nn.gelu approximate=True)
  const float c = 0.7978845608028654f;
  float inner = c * (x + 0.044715f * x * x * x);
  return 0.5f * x * (1.0f + tanhf(inner));
}
__device__ __forceinline__ unsigned short f2bf(float x) {  // RNE f32->bf16
  union { float f; unsigned u; } v; v.f = x;
  unsigned r = v.u + 0x7fffu + ((v.u >> 16) & 1u);
  return (unsigned short)(r >> 16);
}
// async global->LDS, 16B per lane (global addr per-lane; LDS base wave-uniform)
__device__ __forceinline__ void gload_lds16(const void* g, void* l) {
  __builtin_amdgcn_global_load_lds(
      (const __attribute__((address_space(1))) unsigned int*)g,
      (__attribute__((address_space(3))) unsigned int*)l, 16, 0, 0);
}

// ---------------------------------------------------------------- LayerNorm
// TransformerLens LN -> bf16 output (feeds MFMA GEMMs).
__global__ __launch_bounds__(256)
void ln_bf16_kernel(const float* __restrict__ x, const float* __restrict__ w,
                    const float* __restrict__ b, unsigned short* __restrict__ y) {
  __shared__ float sred[4];
  const int r = blockIdx.x;
  const int t = threadIdx.x;
  const int wid = t >> 6, lane = t & 63;
  const float4 v = ((const float4*)(x + (size_t)r * DMODEL))[t];

  float s = v.x + v.y + v.z + v.w;
  s = wave_reduce_sum(s);
  if (lane == 0) sred[wid] = s;
  __syncthreads();
  const float mean = (sred[0] + sred[1] + sred[2] + sred[3]) * (1.0f / DMODEL);
  __syncthreads();

  float4 c;
  c.x = v.x - mean; c.y = v.y - mean; c.z = v.z - mean; c.w = v.w - mean;
  float ss = c.x * c.x + c.y * c.y + c.z * c.z + c.w * c.w;
  ss = wave_reduce_sum(ss);
  if (lane == 0) sred[wid] = ss;
  __syncthreads();
  const float rs =
      rsqrtf((sred[0] + sred[1] + sred[2] + sred[3]) * (1.0f / DMODEL) + 1e-5f);

  const float4 wv = ((const float4*)w)[t];
  const float4 bv = ((const float4*)b)[t];
  ushort4 o;
  o.x = f2bf(c.x * rs * wv.x + bv.x);
  o.y = f2bf(c.y * rs * wv.y + bv.y);
  o.z = f2bf(c.z * rs * wv.z + bv.z);
  o.w = f2bf(c.w * rs * wv.w + bv.w);
  ((ushort4*)(y + (size_t)r * DMODEL))[t] = o;
}

// ------------------------------------------------- weight convert/transpose
// Generic 64x64-tile transpose + f32->bf16: dst[c][r] = src[r][c].
__global__ __launch_bounds__(256)
void transpose_cvt(const float* __restrict__ src, unsigned short* __restrict__ dst,
                   int ld_src, int ld_dst) {
  __shared__ float t[64][68];
  const int r0 = blockIdx.y * 64, c0 = blockIdx.x * 64;
  const int tid = threadIdx.x;
  const int c4 = (tid & 15) * 4, r = tid >> 4;
#pragma unroll
  for (int p = 0; p < 4; ++p) {
    const float4 v = *(const float4*)(src + (size_t)(r0 + r + p * 16) * ld_src + c0 + c4);
    *(float4*)&t[r + p * 16][c4] = v;
  }
  __syncthreads();
  const int r4 = (tid & 15) * 4, c = tid >> 4;
#pragma unroll
  for (int p = 0; p < 4; ++p) {
    const int cc = c + p * 16;
    ushort4 o;
    o.x = f2bf(t[r4 + 0][cc]);
    o.y = f2bf(t[r4 + 1][cc]);
    o.z = f2bf(t[r4 + 2][cc]);
    o.w = f2bf(t[r4 + 3][cc]);
    *(ushort4*)(dst + (size_t)(c0 + cc) * ld_dst + r0 + r4) = o;
  }
}

// W_{Q,K,V}[H, D, DH] f32 -> Bt[h*64+dh][d] bf16 (3 weights, contiguous out).
__global__ __launch_bounds__(256)
void cvt_wqkv(const float* __restrict__ Wq, const float* __restrict__ Wk,
              const float* __restrict__ Wv, unsigned short* __restrict__ out) {
  __shared__ float t[64][68];
  const float* src = (blockIdx.z == 0) ? Wq : (blockIdx.z == 1) ? Wk : Wv;
  unsigned short* dst = out + (size_t)blockIdx.z * (DMODEL * NHEAD * DHEAD);
  const int h = blockIdx.y, d0 = blockIdx.x * 64;
  const int tid = threadIdx.x;
  const int c4 = (tid & 15) * 4, r = tid >> 4;
#pragma unroll
  for (int p = 0; p < 4; ++p) {
    const float4 v = *(const float4*)(src + (size_t)h * (DMODEL * DHEAD) +
                                      (size_t)(d0 + r + p * 16) * DHEAD + c4);
    *(float4*)&t[r + p * 16][c4] = v;
  }
  __syncthreads();
  const int r4 = (tid & 15) * 4, c = tid >> 4;
#pragma unroll
  for (int p = 0; p < 4; ++p) {
    const int cc = c + p * 16;  // dh index
    ushort4 o;
    o.x = f2bf(t[r4 + 0][cc]);
    o.y = f2bf(t[r4 + 1][cc]);
    o.z = f2bf(t[r4 + 2][cc]);
    o.w = f2bf(t[r4 + 3][cc]);
    *(ushort4*)(dst + (size_t)(h * 64 + cc) * DMODEL + d0 + r4) = o;
  }
}

// ---------------------------------------------------------------- MFMA GEMM
// C[M x N] = A[M x K](bf16,row-major) @ Bt[N x K](bf16,row-major)^T + bias.
// m97 structure: 128x128 tile, BK=32, 4 waves, global_load_lds w16, 2 barriers.
// EPI: 0 = f32 store; 1 = bf16 gelu store; 2 = f32 + addend; 3 = f32 accum;
//      5 = bf16 store.
template <int EPI>
__global__ __launch_bounds__(256)
void gemm_bf16(const unsigned short* __restrict__ A,
               const unsigned short* __restrict__ Bt,
               const float* __restrict__ bias, const float* __restrict__ addend,
               void* __restrict__ Cout, int ldc, int K) {
  __shared__ unsigned short As[128 * 32];  // [row][k] linear, rows of 64B
  __shared__ unsigned short Bs[128 * 32];
  const int tid = threadIdx.x;
  const int w = tid >> 6, lane = tid & 63;
  const int wr = w >> 1, wc = w & 1;           // wave -> 64x64 quadrant
  const int m0 = blockIdx.x * 128, n0 = blockIdx.y * 128;

  f32x4 acc[4][4];
#pragma unroll
  for (int m = 0; m < 4; ++m)
#pragma unroll
    for (int n = 0; n < 4; ++n) acc[m][n] = (f32x4){0.f, 0.f, 0.f, 0.f};

  const int srow = w * 32 + (lane >> 2);       // staging row within tile
  const int scol = (lane & 3) * 8;             // staging k-offset (8 bf16 = 16B)

  for (int k0 = 0; k0 < K; k0 += 32) {
    __syncthreads();  // all waves done reading previous tile
#pragma unroll
    for (int it = 0; it < 2; ++it) {
      const int row = srow + it * 16;
      gload_lds16(A + (size_t)(m0 + row) * K + k0 + scol,
                  &As[(w * 32 + it * 16) * 32]);
      gload_lds16(Bt + (size_t)(n0 + row) * K + k0 + scol,
                  &Bs[(w * 32 + it * 16) * 32]);
    }
    __syncthreads();  // staging complete (vmcnt drained at barrier)

    bf16x8v af[4], bf[4];
#pragma unroll
    for (int m = 0; m < 4; ++m)
      af[m] = *(const bf16x8v*)&As[(wr * 64 + m * 16 + (lane & 15)) * 32 + (lane >> 4) * 8];
#pragma unroll
    for (int n = 0; n < 4; ++n)
      bf[n] = *(const bf16x8v*)&Bs[(wc * 64 + n * 16 + (lane & 15)) * 32 + (lane >> 4) * 8];
#pragma unroll
    for (int m = 0; m < 4; ++m)
#pragma unroll
      for (int n = 0; n < 4; ++n)
        acc[m][n] = __builtin_amdgcn_mfma_f32_16x16x32_bf16(af[m], bf[n], acc[m][n], 0, 0, 0);
  }

  // epilogue: C/D layout col = lane&15, row = (lane>>4)*4 + reg  [m89]
#pragma unroll
  for (int m = 0; m < 4; ++m) {
    const int row = m0 + wr * 64 + m * 16 + (lane >> 4) * 4;
#pragma unroll
    for (int n = 0; n < 4; ++n) {
      const int col = n0 + wc * 64 + n * 16 + (lane & 15);
      const float bcol = bias[col];
      const f32x4 a = acc[m][n];
#pragma unroll
      for (int r = 0; r < 4; ++r) {
        const float val = a[r] + bcol;
        const size_t off = (size_t)(row + r) * ldc + col;
        if (EPI == 0) {
          ((float*)Cout)[off] = val;
        } else if (EPI == 1) {
          ((unsigned short*)Cout)[off] = f2bf(gelu_new(val));
        } else if (EPI == 2) {
          ((float*)Cout)[off] = val + addend[off];
        } else if (EPI == 3) {
          ((float*)Cout)[off] += val;
        } else {  // EPI == 5
          ((unsigned short*)Cout)[off] = f2bf(val);
        }
      }
    }
  }
}

// ------------------------------------------- fused QKV GEMM (N = 3072)
// C[4096 x 3072] = xln @ (WQt||WKt||WVt)^T; per-block epilogue switch:
// blockIdx.y>>3 = 0 -> Qb (bf16 row-major, PRE-SCALED by QSCALE),
// 1 -> Kf (attn A-fragment order), 2 -> Vf (attn A-fragment order, V^T).
// Fragment layouts (per bh, 131072 ushorts = 2048x64):
//   Kf: off = kc*4096 + n*1024 + ks*512 + lr*32 + lg*8 + e
//       holds K[key = kc*64 + n*16 + lr][dim = ks*32 + lg*8 + e]
//   Vf: off = kc*4096 + nd*1024 + ks*512 + lr*32 + lg*8 + e
//       holds V^T[d = nd*16 + lr][key = kc*64 + ks*32 + lg*8 + e]
// -> attn's per-lane 16B fragment load (lane = lg*16+lr) covers one
//    contiguous aligned 1KB block per (tile, ks): fully coalesced.
__global__ __launch_bounds__(256)
void gemm_qkv(const unsigned short* __restrict__ A,
              const unsigned short* __restrict__ Bt,  // [3072][1024]
              const float* __restrict__ bQ, const float* __restrict__ bK,
              const float* __restrict__ bV,
              unsigned short* __restrict__ Qb, unsigned short* __restrict__ Kf,
              unsigned short* __restrict__ Vf) {
  __shared__ unsigned short As[128 * 32];
  __shared__ unsigned short Bs[128 * 32];
  const int tid = threadIdx.x;
  const int w = tid >> 6, lane = tid & 63;
  const int wr = w >> 1, wc = w & 1;
  const int m0 = blockIdx.x * 128, n0 = blockIdx.y * 128;

  f32x4 acc[4][4];
#pragma unroll
  for (int m = 0; m < 4; ++m)
#pragma unroll
    for (int n = 0; n < 4; ++n) acc[m][n] = (f32x4){0.f, 0.f, 0.f, 0.f};

  const int srow = w * 32 + (lane >> 2);
  const int scol = (lane & 3) * 8;

  for (int k0 = 0; k0 < DMODEL; k0 += 32) {
    __syncthreads();
#pragma unroll
    for (int it = 0; it < 2; ++it) {
      const int row = srow + it * 16;
      gload_lds16(A + (size_t)(m0 + row) * DMODEL + k0 + scol,
                  &As[(w * 32 + it * 16) * 32]);
      gload_lds16(Bt + (size_t)(n0 + row) * DMODEL + k0 + scol,
                  &Bs[(w * 32 + it * 16) * 32]);
    }
    __syncthreads();

    bf16x8v af[4], bf[4];
#pragma unroll
    for (int m = 0; m < 4; ++m)
      af[m] = *(const bf16x8v*)&As[(wr * 64 + m * 16 + (lane & 15)) * 32 + (lane >> 4) * 8];
#pragma unroll
    for (int n = 0; n < 4; ++n)
      bf[n] = *(const bf16x8v*)&Bs[(wc * 64 + n * 16 + (lane & 15)) * 32 + (lane >> 4) * 8];
#pragma unroll
    for (int m = 0; m < 4; ++m)
#pragma unroll
      for (int n = 0; n < 4; ++n)
        acc[m][n] = __builtin_amdgcn_mfma_f32_16x16x32_bf16(af[m], bf[n], acc[m][n], 0, 0, 0);
  }

  const int which = blockIdx.y >> 3;  // uniform per block: 0=Q, 1=K, 2=V
  const float* bias = (which == 0) ? bQ : (which == 1) ? bK : bV;
#pragma unroll
  for (int m = 0; m < 4; ++m) {
    const int row = m0 + wr * 64 + m * 16 + (lane >> 4) * 4;  // r=0 seq row
    const int bb = row >> 11, s = row & 2047;  // r-invariant except low bits
#pragma unroll
    for (int n = 0; n < 4; ++n) {
      const int ck = (n0 + wc * 64 + n * 16 + (lane & 15)) & 1023;  // in-matrix col
      const float bcol = bias[ck];
      const f32x4 a = acc[m][n];
      if (which == 0) {  // Q row-major, pre-scaled
#pragma unroll
        for (int r = 0; r < 4; ++r)
          Qb[(size_t)(row + r) * DMODEL + ck] = f2bf((a[r] + bcol) * QSCALE);
      } else if (which == 1) {  // K -> fragment order
        const int hh = ck >> 6, dh = ck & 63;
        const int ks = dh >> 5, lgw = (dh >> 3) & 3, e = dh & 7;
        const int kc = s >> 6, nf = (s >> 4) & 3, lrw = s & 15;
        const size_t off = (size_t)(bb * 16 + hh) * (SEQ * DHEAD) +
                           kc * 4096 + nf * 1024 + ks * 512 + lrw * 32 + lgw * 8 + e;
#pragma unroll
        for (int r = 0; r < 4; ++r)
          Kf[off + r * 32] = f2bf(a[r] + bcol);
      } else {  // V -> V^T fragment order; r=0..3 -> consecutive e (ushort4)
        const int hh = ck >> 6, dh = ck & 63;
        const int nd = dh >> 4, lrv = dh & 15;
        const int kc = s >> 6, ks = (s >> 5) & 1, lgw = (s >> 3) & 3, e0 = s & 7;
        const size_t off = (size_t)(bb * 16 + hh) * (SEQ * DHEAD) +
                           kc * 4096 + nd * 1024 + ks * 512 + lrv * 32 + lgw * 8 + e0;
        ushort4 o;
        o.x = f2bf(a[0] + bcol); o.y = f2bf(a[1] + bcol);
        o.z = f2bf(a[2] + bcol); o.w = f2bf(a[3] + bcol);
        *(ushort4*)&Vf[off] = o;
      }
    }
  }
}

// ---------------------------------------------------------------- Attention
// Causal MFMA flash attention, bf16 inputs, fp32 accum, swapped-operand form
// (S^T: col=q, row=key -> lane-local softmax stats, 2 shfl_xor per reduce).
// Q pre-scaled by 1/sqrt(DH)*log2(e) -> softmax via raw v_exp_f32 (exp2).
// K/V are in FRAGMENT ORDER (see gemm_qkv): each 16B fragment load's 64
// lanes cover one contiguous 1KB block -> 16 cache lines/instr (was 64,
// which saturated the per-CU L1 pipe: R8 time was invariant to occupancy).
// 512 blocks x 8 waves; wave w<4 -> qblk=pr, w>=4 -> qblk=31-pr (per-SIMD
// chunk total = 33, uniform). bid%8 == bh%8 -> (b,h) K/V slab stays in one
// XCD's L2. Next-chunk K prefetch + early V loads; mask only on diagonal.
__global__ __launch_bounds__(512)
void attn_mfma_kernel(const unsigned short* __restrict__ Qb,
                      const unsigned short* __restrict__ Kf,
                      const unsigned short* __restrict__ Vf,
                      unsigned short* __restrict__ Zb) {
  __shared__ unsigned short Ps[8][16][72];  // per-wave P: [qloc][key], padded
  const int tid = threadIdx.x;
  const int w = tid >> 6, lane = tid & 63;
  const int lg = lane >> 4, lr = lane & 15;
  const int bh = blockIdx.x & 31;          // b*16 + h  (bid%8 == bh%8)
  const int pr = blockIdx.x >> 5;          // pair index 0..15
  const int h = bh & 15, b = bh >> 4;
  const size_t q_base = (size_t)b * SEQ * DMODEL + (size_t)h * DHEAD;
  const unsigned short* Kfb = Kf + (size_t)bh * (SEQ * DHEAD);
  const unsigned short* Vfb = Vf + (size_t)bh * (SEQ * DHEAD);
  const int loff = lr * 32 + lg * 8;       // per-lane fragment offset

  const int qblk = (w < 4) ? pr : (31 - pr);
  const int q0 = qblk * 64 + (w & 3) * 16; // wave's first query
  const int myq = q0 + lr;                 // this lane's query (col index)

  // Q B-fragment: col=lr -> query myq, k(dim) = ks*32 + lg*8 + 0..7
  bf16x8v bq[2];
#pragma unroll
  for (int ks = 0; ks < 2; ++ks)
    bq[ks] = *(const bf16x8v*)&Qb[q_base + (size_t)myq * DMODEL + ks * 32 + lg * 8];

  f32x4 accz[4];
#pragma unroll
  for (int nd = 0; nd < 4; ++nd) accz[nd] = (f32x4){0.f, 0.f, 0.f, 0.f};
  float mq = -3.0e38f, Lq = 0.0f;

  // prefetch K fragments for first chunk (coalesced 1KB blocks)
  bf16x8v kf[2][4];
#pragma unroll
  for (int ks = 0; ks < 2; ++ks)
#pragma unroll
    for (int n = 0; n < 4; ++n)
      kf[ks][n] = *(const bf16x8v*)&Kfb[n * 1024 + ks * 512 + loff];

  for (int kc = 0; kc <= qblk; ++kc) {
    // ---- QK^T swapped: accs[n] = K_tile_n . Q^T ; row=key(4lg+r), col=q(lr)
    f32x4 accs[4];
#pragma unroll
    for (int n = 0; n < 4; ++n) accs[n] = (f32x4){0.f, 0.f, 0.f, 0.f};
#pragma unroll
    for (int ks = 0; ks < 2; ++ks)
#pragma unroll
      for (int n = 0; n < 4; ++n)
        accs[n] = __builtin_amdgcn_mfma_f32_16x16x32_bf16(kf[ks][n], bq[ks], accs[n], 0, 0, 0);

    // ---- prefetch next chunk's K fragments (hidden under softmax+PV)
    if (kc < qblk) {
#pragma unroll
      for (int ks = 0; ks < 2; ++ks)
#pragma unroll
        for (int n = 0; n < 4; ++n)
          kf[ks][n] = *(const bf16x8v*)
              &Kfb[(kc + 1) * 4096 + n * 1024 + ks * 512 + loff];
    }
    // ---- V fragments issued early (independent of softmax)
    bf16x8v vf[2][4];
#pragma unroll
    for (int ks = 0; ks < 2; ++ks)
#pragma unroll
      for (int nd = 0; nd < 4; ++nd)
        vf[ks][nd] = *(const bf16x8v*)
            &Vfb[kc * 4096 + nd * 1024 + ks * 512 + loff];

    // ---- mask only on diagonal chunk; lane-local max (scores pre-scaled)
    float mx = -3.0e38f;
    if (kc == qblk) {
#pragma unroll
      for (int n = 0; n < 4; ++n)
#pragma unroll
        for (int r = 0; r < 4; ++r) {
          float s = accs[n][r];
          s = (kc * 64 + n * 16 + 4 * lg + r <= myq) ? s : -3.0e38f;  // causal
          accs[n][r] = s; mx = fmaxf(mx, s);
        }
    } else {
#pragma unroll
      for (int n = 0; n < 4; ++n)
#pragma unroll
        for (int r = 0; r < 4; ++r) mx = fmaxf(mx, accs[n][r]);
    }
    mx = fmaxf(mx, __shfl_xor(mx, 16, 64));
    mx = fmaxf(mx, __shfl_xor(mx, 32, 64));
    const float mn = fmaxf(mq, mx);
    const float c0 = __builtin_amdgcn_exp2f(mq - mn);
    // ---- exp2, packed P^T writes to LDS [q][key], lane-local partial sum
    float sum = 0.0f;
#pragma unroll
    for (int n = 0; n < 4; ++n) {
      ushort4 pk;
      float e0 = __builtin_amdgcn_exp2f(accs[n][0] - mn);
      float e1 = __builtin_amdgcn_exp2f(accs[n][1] - mn);
      float e2 = __builtin_amdgcn_exp2f(accs[n][2] - mn);
      float e3 = __builtin_amdgcn_exp2f(accs[n][3] - mn);
      sum += e0 + e1 + e2 + e3;
      pk.x = f2bf(e0); pk.y = f2bf(e1); pk.z = f2bf(e2); pk.w = f2bf(e3);
      *(ushort4*)&Ps[w][lr][n * 16 + 4 * lg] = pk;
    }
    sum += __shfl_xor(sum, 16, 64);
    sum += __shfl_xor(sum, 32, 64);
    Lq = Lq * c0 + sum;
    mq = mn;
#pragma unroll
    for (int nd = 0; nd < 4; ++nd) accz[nd] *= c0;
    // ---- P A-side read (same-wave DS ordering): row=q(lr), k=keys
    bf16x8v ap[2];
#pragma unroll
    for (int ks = 0; ks < 2; ++ks)
      ap[ks] = *(const bf16x8v*)&Ps[w][lr][ks * 32 + lg * 8];
    // ---- PV swapped: accz[nd] = V^T_tile . P ; row=d(4lg+r), col=q(lr)
#pragma unroll
    for (int ks = 0; ks < 2; ++ks)
#pragma unroll
      for (int nd = 0; nd < 4; ++nd)
        accz[nd] = __builtin_amdgcn_mfma_f32_16x16x32_bf16(vf[ks][nd], ap[ks], accz[nd], 0, 0, 0);
  }
  // ---- epilogue: lane's query row, d = nd*16 + 4lg + (0..3) contiguous
  const float rL = 1.0f / Lq;
  unsigned short* zrow = Zb + (size_t)((size_t)b * SEQ + myq) * DMODEL + h * DHEAD;
#pragma unroll
  for (int nd = 0; nd < 4; ++nd) {
    ushort4 o;
    o.x = f2bf(accz[nd][0] * rL);
    o.y = f2bf(accz[nd][1] * rL);
    o.z = f2bf(accz[nd][2] * rL);
    o.w = f2bf(accz[nd][3] * rL);
    *(ushort4*)(zrow + nd * 16 + 4 * lg) = o;
  }
}

// ---------------------------------------------------------------- launch
extern "C" void kernel_launch(void* const* d_in, const int* in_sizes, int n_in,
                              void* d_out, int out_size, void* d_ws, size_t ws_size,
                              hipStream_t stream) {
  const float* resid_pre = (const float*)d_in[0];
  const float* ln1_w = (const float*)d_in[1];
  const float* ln1_b = (const float*)d_in[2];
  const float* W_Q = (const float*)d_in[3];
  const float* W_K = (const float*)d_in[4];
  const float* W_V = (const float*)d_in[5];
  const float* W_O = (const float*)d_in[6];
  const float* b_Q = (const float*)d_in[7];
  const float* b_K = (const float*)d_in[8];
  const float* b_V = (const float*)d_in[9];
  const float* b_O = (const float*)d_in[10];
  const float* ln2_w = (const float*)d_in[11];
  const float* ln2_b = (const float*)d_in[12];
  const float* W_in = (const float*)d_in[13];
  const float* b_in = (const float*)d_in[14];
  const float* W_out = (const float*)d_in[15];
  const float* b_out = (const float*)d_in[16];
  (void)in_sizes; (void)n_in; (void)out_size; (void)ws_size;

  float* out = (float*)d_out;
  char* w8 = (char*)d_ws;
  // Workspace map (56 MB used):
  //  [0,8M)    xln_b (LN1 out / LN2 out) ; Zb aliases (dead-time disjoint)
  //  [8,14M)   WQt/WKt/WVt  bf16 [3072,1024] contiguous (B^T layout)
  //  [14,16M)  WOt   bf16 [1024,1024]
  //  [16,24M)  Wint  bf16 [4096,1024]
  //  [24,32M)  Woutt bf16 [1024,4096]
  //  [32,40M)  Qb bf16 [4096,1024]   \
  //  [40,48M)  Kf bf16 frag-order     } dead after attn; hid_b [32,64M) reuses
  //  [48,56M)  Vf bf16 frag-order    /
  unsigned short* xln_b = (unsigned short*)(w8);
  unsigned short* Zb    = (unsigned short*)(w8);
  unsigned short* WQt   = (unsigned short*)(w8 + (8u << 20));
  unsigned short* WOt   = (unsigned short*)(w8 + (14u << 20));
  unsigned short* Wint  = (unsigned short*)(w8 + (16u << 20));
  unsigned short* Woutt = (unsigned short*)(w8 + (24u << 20));
  unsigned short* Qb    = (unsigned short*)(w8 + (32u << 20));
  unsigned short* Kf    = (unsigned short*)(w8 + (40u << 20));
  unsigned short* Vf    = (unsigned short*)(w8 + (48u << 20));
  unsigned short* hid_b = (unsigned short*)(w8 + (32u << 20));

  // weight conversions (run every call; d_ws is re-poisoned)
  cvt_wqkv<<<dim3(16, 16, 3), 256, 0, stream>>>(W_Q, W_K, W_V, WQt);
  transpose_cvt<<<dim3(16, 16), 256, 0, stream>>>(W_O, WOt, DMODEL, DMODEL);
  transpose_cvt<<<dim3(64, 16), 256, 0, stream>>>(W_in, Wint, DMLP, DMODEL);
  transpose_cvt<<<dim3(16, 64), 256, 0, stream>>>(W_out, Woutt, DMODEL, DMLP);

  // LN1 -> bf16
  ln_bf16_kernel<<<ROWS, 256, 0, stream>>>(resid_pre, ln1_w, ln1_b, xln_b);
  // fused QKV projection -> Qb (pre-scaled), Kf, Vf (fragment order)
  gemm_qkv<<<dim3(32, 24), 256, 0, stream>>>(xln_b, WQt, b_Q, b_K, b_V, Qb, Kf, Vf);
  // causal MFMA attention -> Zb (aliases xln_b; LN1 output is dead now)
  attn_mfma_kernel<<<512, 512, 0, stream>>>(Qb, Kf, Vf, Zb);
  // W_O projection + bias + residual -> d_out = resid_mid
  dim3 g1024(ROWS / 128, 1024 / 128);
  gemm_bf16<2><<<g1024, 256, 0, stream>>>(Zb, WOt, b_O, resid_pre, out, DMODEL, DMODEL);
  // LN2 -> bf16 (overwrites Zb region after W_O consumed it)
  ln_bf16_kernel<<<ROWS, 256, 0, stream>>>(out, ln2_w, ln2_b, xln_b);
  // MLP in + GELU -> bf16 hid
  dim3 gin(ROWS / 128, DMLP / 128);
  gemm_bf16<1><<<gin, 256, 0, stream>>>(xln_b, Wint, b_in, nullptr, hid_b, DMLP, DMODEL);
  // MLP out, accumulate into resid_mid in d_out
  gemm_bf16<3><<<g1024, 256, 0, stream>>>(hid_b, Woutt, b_out, nullptr, out, DMODEL, DMLP);
}